// Round 5
// baseline (196.829 us; speedup 1.0000x reference)
//
#include <hip/hip_runtime.h>
#include <hip/hip_bf16.h>

// Embedding gather: out[b,s,:] = weight[token_ids[b,s],:]
// BATCH=4, SEQ=4096, DIM=1024, VOCAB=32000, float32.
// One wave (64 lanes) per token row: 64 lanes x 16 B x 4 chunks = 4096 B = row.
// Output is write-once / never-read -> nontemporal stores keep the 131 MB
// weight table resident in L2/LLC for the gather reads.
// Note: __builtin_nontemporal_store requires a true vector type, not
// HIP_vector_type<float,4> -> use clang ext_vector_type(4).

typedef float floatx4 __attribute__((ext_vector_type(4)));

#define DIM 1024
#define F4_PER_ROW (DIM / 4)   // 256 float4 per row
#define TOKENS_PER_BLOCK 4

__global__ __launch_bounds__(256) void embedding_gather_kernel(
    const int* __restrict__ token_ids,
    const floatx4* __restrict__ weight,   // [VOCAB, DIM/4]
    floatx4* __restrict__ out,            // [N_TOKENS, DIM/4]
    int n_tokens)
{
    const int wave = threadIdx.x >> 6;        // 0..3
    const int lane = threadIdx.x & 63;        // 0..63
    const int token_slot = blockIdx.x * TOKENS_PER_BLOCK + wave;
    if (token_slot >= n_tokens) return;

    const int tok = token_ids[token_slot];    // wave-uniform scalar load
    const floatx4* __restrict__ src = weight + (size_t)tok * F4_PER_ROW;
    floatx4* __restrict__ dst = out + (size_t)token_slot * F4_PER_ROW;

    // All 4 loads in flight before stores (MLP), stores bypass cache (NT).
    floatx4 v0 = src[lane];
    floatx4 v1 = src[lane + 64];
    floatx4 v2 = src[lane + 128];
    floatx4 v3 = src[lane + 192];
    __builtin_nontemporal_store(v0, dst + lane);
    __builtin_nontemporal_store(v1, dst + lane + 64);
    __builtin_nontemporal_store(v2, dst + lane + 128);
    __builtin_nontemporal_store(v3, dst + lane + 192);
}

extern "C" void kernel_launch(void* const* d_in, const int* in_sizes, int n_in,
                              void* d_out, int out_size, void* d_ws, size_t ws_size,
                              hipStream_t stream) {
    const int* token_ids = (const int*)d_in[0];        // [4, 4096] int32
    const floatx4* weight = (const floatx4*)d_in[1];   // [32000, 1024] f32
    floatx4* out = (floatx4*)d_out;                    // [4, 4096, 1024] f32

    const int n_tokens = in_sizes[0];                  // 16384
    dim3 grid((n_tokens + TOKENS_PER_BLOCK - 1) / TOKENS_PER_BLOCK);
    dim3 block(256);
    embedding_gather_kernel<<<grid, block, 0, stream>>>(token_ids, weight, out, n_tokens);
}

// Round 6
// 196.387 us; speedup vs baseline: 1.0023x; 1.0023x over previous
//
#include <hip/hip_runtime.h>
#include <hip/hip_bf16.h>

// Embedding gather: out[b,s,:] = weight[token_ids[b,s],:]
// BATCH=4, SEQ=4096, DIM=1024, VOCAB=32000, float32.
// Each wave handles 4 tokens: one uniform int4 id load (amortizes the
// id->row latency chain 4x), then 16 independent float4 row-chunk loads
// (16 KB in flight per wave) followed by 16 NT stores (output is
// write-once; bypass L2 so gathered weight rows stay resident).

typedef float floatx4 __attribute__((ext_vector_type(4)));

#define DIM 1024
#define F4_PER_ROW (DIM / 4)     // 256 float4 per row
#define TOKENS_PER_WAVE 4
#define WAVES_PER_BLOCK 4        // block = 256 threads = 16 tokens

__global__ __launch_bounds__(256) void embedding_gather_kernel(
    const int* __restrict__ token_ids,
    const floatx4* __restrict__ weight,   // [VOCAB, DIM/4]
    floatx4* __restrict__ out,            // [N_TOKENS, DIM/4]
    int n_tokens)
{
    const int wave = threadIdx.x >> 6;        // 0..3
    const int lane = threadIdx.x & 63;        // 0..63
    const int t0 = (blockIdx.x * WAVES_PER_BLOCK + wave) * TOKENS_PER_WAVE;
    if (t0 >= n_tokens) return;

    // Wave-uniform 16B id load: 4 token ids in one transaction.
    const int4 ids = *(const int4*)(token_ids + t0);
    const int tok[TOKENS_PER_WAVE] = {ids.x, ids.y, ids.z, ids.w};

    // Issue all 16 row-chunk loads before any store (max MLP).
    floatx4 v[TOKENS_PER_WAVE][4];
#pragma unroll
    for (int i = 0; i < TOKENS_PER_WAVE; ++i) {
        const floatx4* __restrict__ src = weight + (size_t)tok[i] * F4_PER_ROW;
#pragma unroll
        for (int c = 0; c < 4; ++c)
            v[i][c] = src[lane + 64 * c];
    }

#pragma unroll
    for (int i = 0; i < TOKENS_PER_WAVE; ++i) {
        floatx4* __restrict__ dst = out + (size_t)(t0 + i) * F4_PER_ROW;
#pragma unroll
        for (int c = 0; c < 4; ++c)
            __builtin_nontemporal_store(v[i][c], dst + lane + 64 * c);
    }
}

extern "C" void kernel_launch(void* const* d_in, const int* in_sizes, int n_in,
                              void* d_out, int out_size, void* d_ws, size_t ws_size,
                              hipStream_t stream) {
    const int* token_ids = (const int*)d_in[0];        // [4, 4096] int32
    const floatx4* weight = (const floatx4*)d_in[1];   // [32000, 1024] f32
    floatx4* out = (floatx4*)d_out;                    // [4, 4096, 1024] f32

    const int n_tokens = in_sizes[0];                  // 16384
    const int tokens_per_block = TOKENS_PER_WAVE * WAVES_PER_BLOCK;  // 16
    dim3 grid((n_tokens + tokens_per_block - 1) / tokens_per_block); // 1024
    dim3 block(256);
    embedding_gather_kernel<<<grid, block, 0, stream>>>(token_ids, weight, out, n_tokens);
}